// Round 9
// baseline (227.058 us; speedup 1.0000x reference)
//
#include <hip/hip_runtime.h>
#include <math.h>

#define Bsz 128
#define Usz 16
#define Dsz 256
#define Nsz 1024
#define Osz 256

typedef __attribute__((ext_vector_type(4))) float f32x4;
typedef __attribute__((ext_vector_type(8))) short bf16x8;
typedef __attribute__((ext_vector_type(4))) unsigned int u32x4;

union cell_u { u32x4 u; bf16x8 b; };

struct F8 { f32x4 lo, hi; };

__device__ __forceinline__ unsigned int fbits(float f) {
    union { float f; unsigned int u; } v; v.f = f; return v.u;
}
// pack two f32 -> (bf16(hi)<<16)|bf16(lo) by truncation: 1 v_perm_b32
__device__ __forceinline__ unsigned int pk(float lo, float hi) {
    return __builtin_amdgcn_perm(fbits(hi), fbits(lo), 0x07060302u);
}
__device__ __forceinline__ bf16x8 pkF8(F8 f, float s) {
    f.lo *= s; f.hi *= s;
    cell_u r;
    r.u[0] = pk(f.lo[0], f.lo[1]); r.u[1] = pk(f.lo[2], f.lo[3]);
    r.u[2] = pk(f.hi[0], f.hi[1]); r.u[3] = pk(f.hi[2], f.hi[3]);
    return r.b;
}
__device__ __forceinline__ F8 ld8c(const float* p) {
    F8 r; r.lo = *(const f32x4*)p; r.hi = *(const f32x4*)(p + 4); return r;
}
__device__ __forceinline__ F8 ld8s(const float* p, int str) {
    F8 r;
    r.lo[0] = p[0];               r.lo[1] = p[(size_t)str];
    r.lo[2] = p[2 * (size_t)str]; r.lo[3] = p[3 * (size_t)str];
    r.hi[0] = p[4 * (size_t)str]; r.hi[1] = p[5 * (size_t)str];
    r.hi[2] = p[6 * (size_t)str]; r.hi[3] = p[7 * (size_t)str];
    return r;
}

// ---------------- lr = softmax_u(X·alr / T) ----------------
__global__ __launch_bounds__(256)
void lr_kernel(const float* __restrict__ X, const float* __restrict__ alr,
               const float* __restrict__ temp, float* __restrict__ lr)
{
    const int b = blockIdx.x;
    const int t = threadIdx.x;
    const int u = t >> 4;
    const int l = t & 15;
    const float* xp = X + ((size_t)b * Usz + u) * Dsz;
    const float* ap = alr + (size_t)u * Dsz;
    float s = 0.f;
    for (int d = l; d < Dsz; d += 16) s += xp[d] * ap[d];
    s += __shfl_down(s, 8, 16);
    s += __shfl_down(s, 4, 16);
    s += __shfl_down(s, 2, 16);
    s += __shfl_down(s, 1, 16);
    __shared__ float logits[16];
    if (l == 0) logits[u] = s;
    __syncthreads();
    if (t < 16) {
        const float T = temp[0];
        float m = -1e30f;
        #pragma unroll
        for (int i = 0; i < 16; i++) m = fmaxf(m, logits[i] / T);
        float sum = 0.f;
        #pragma unroll
        for (int i = 0; i < 16; i++) sum += expf(logits[i] / T - m);
        lr[(size_t)b * Usz + t] = expf(logits[t] / T - m) / sum;
    }
}

// ================= SPLIT-K PATH (primary) =================
// state partials: Cp[ks][u][m128][n1024] += chunk of [X | state*sr]·[Win ; W]
// grid 2048 = ks4 x mt2 x nt16 x u16 -> 8 blocks/CU, 32 waves/CU (max occ).
// Latency hidden by TLP (8 waves/SIMD), not by in-wave prefetch.
__global__ __launch_bounds__(256)
void state_split(const float* __restrict__ X, const float* __restrict__ state,
                 const float* __restrict__ W, const float* __restrict__ Win,
                 const float* __restrict__ sr, float* __restrict__ part)
{
    const int id = blockIdx.x;
    const int u  = id & 15;
    const int nt = (id >> 4) & 15;
    const int mt = (id >> 8) & 1;
    const int ks = id >> 9;               // 0..3, K-chunk of 320

    const int tid  = threadIdx.x;
    const int wave = tid >> 6, lane = tid & 63;
    const int l16  = lane & 15, kgl = lane >> 4;
    const int wm = wave & 1, wn = wave >> 1;

    const int row0 = mt * 64 + wm * 32 + l16;
    const int col0 = nt * 64 + wn * 32 + l16;
    const int k0   = ks * 320;

    const float sru = sr[u];

    const float* Ax0 = X + ((size_t)row0 * Usz + u) * Dsz;
    const float* Ax1 = X + ((size_t)(row0 + 16) * Usz + u) * Dsz;
    const float* Ae0 = state + ((size_t)row0 * Usz + u) * Nsz;
    const float* Ae1 = state + ((size_t)(row0 + 16) * Usz + u) * Nsz;
    const float* Bf  = Win + (size_t)u * Dsz * Nsz + col0;
    const float* Be  = W   + (size_t)u * Nsz * Nsz + col0;

    f32x4 acc[2][2] = {};

    for (int s = 0; s < 10; ++s) {
        const int kb = k0 + s * 32 + kgl * 8;
        F8 a0, a1, b0, b1;
        if (kb < Dsz) {
            a0 = ld8c(Ax0 + kb);
            a1 = ld8c(Ax1 + kb);
            const float* pb = Bf + (size_t)kb * Nsz;
            b0 = ld8s(pb, Nsz);
            b1 = ld8s(pb + 16, Nsz);
        } else {
            const int kk = kb - Dsz;
            a0 = ld8c(Ae0 + kk);
            a1 = ld8c(Ae1 + kk);
            const float* pb = Be + (size_t)kk * Nsz;
            b0 = ld8s(pb, Nsz);
            b1 = ld8s(pb + 16, Nsz);
        }
        const float asc = (k0 + s * 32 < Dsz) ? 1.f : sru;   // uniform per step
        const bf16x8 af0 = pkF8(a0, asc), af1 = pkF8(a1, asc);
        const bf16x8 bf0 = pkF8(b0, 1.f), bf1 = pkF8(b1, 1.f);
        acc[0][0] = __builtin_amdgcn_mfma_f32_16x16x32_bf16(af0, bf0, acc[0][0], 0, 0, 0);
        acc[0][1] = __builtin_amdgcn_mfma_f32_16x16x32_bf16(af0, bf1, acc[0][1], 0, 0, 0);
        acc[1][0] = __builtin_amdgcn_mfma_f32_16x16x32_bf16(af1, bf0, acc[1][0], 0, 0, 0);
        acc[1][1] = __builtin_amdgcn_mfma_f32_16x16x32_bf16(af1, bf1, acc[1][1], 0, 0, 0);
    }

    // C/D layout: col=lane&15, row=(lane>>4)*4+reg (HW-verified R3-R8)
    float* base = part + ((size_t)ks * 16 + u) * 128 * 1024;
    #pragma unroll
    for (int ni = 0; ni < 2; ni++) {
        const int gcol = nt * 64 + wn * 32 + ni * 16 + l16;
        #pragma unroll
        for (int mi = 0; mi < 2; mi++) {
            #pragma unroll
            for (int rg = 0; rg < 4; rg++) {
                const int grow = mt * 64 + wm * 32 + mi * 16 + kgl * 4 + rg;
                base[(size_t)grow * 1024 + gcol] = acc[mi][ni][rg];
            }
        }
    }
}

// sum 4 partials + bias -> tanh -> lr blend -> out0. 2048 blocks x 256 thr.
__global__ __launch_bounds__(256)
void state_reduce(const float* __restrict__ part, const float* __restrict__ state,
                  const float* __restrict__ bias, const float* __restrict__ lr,
                  float* __restrict__ out0)
{
    const size_t i = (size_t)blockIdx.x * 256 + threadIdx.x;   // 0..524287
    const size_t base = i * 4;                 // flat [m][u][n]
    const int m = (int)(base >> 14);
    const int u = (int)((base >> 10) & 15);
    const int n = (int)(base & 1023);

    const size_t pb = ((size_t)u * 128 + m) * 1024 + n;
    const size_t slab = (size_t)16 * 128 * 1024;
    f32x4 s = *(const f32x4*)(part + pb);
    s += *(const f32x4*)(part + pb + slab);
    s += *(const f32x4*)(part + pb + 2 * slab);
    s += *(const f32x4*)(part + pb + 3 * slab);

    const f32x4 bi = *(const f32x4*)(bias + (size_t)u * Nsz + n);
    const f32x4 sv = *(const f32x4*)(state + base);
    const float lv = lr[m * Usz + u];
    f32x4 o;
    o[0] = (1.f - lv) * sv[0] + lv * tanhf(s[0] + bi[0]);
    o[1] = (1.f - lv) * sv[1] + lv * tanhf(s[1] + bi[1]);
    o[2] = (1.f - lv) * sv[2] + lv * tanhf(s[2] + bi[2]);
    o[3] = (1.f - lv) * sv[3] + lv * tanhf(s[3] + bi[3]);
    *(f32x4*)(out0 + base) = o;
}

// out partials: wave = 16m x 16n, block = 4 waves along m (64m x 16n),
// grid 2048 = ks4 x mseg2 x ot16 x u16 -> 8 blocks/CU.
__global__ __launch_bounds__(256)
void out_split(const float* __restrict__ ns, const float* __restrict__ Wout,
               float* __restrict__ part)
{
    const int id = blockIdx.x;
    const int u    = id & 15;
    const int ot   = (id >> 4) & 15;
    const int mseg = (id >> 8) & 1;
    const int ks   = id >> 9;             // K-chunk of 256

    const int wave = threadIdx.x >> 6, lane = threadIdx.x & 63;
    const int l16  = lane & 15, kgl = lane >> 4;
    const int mtw  = mseg * 4 + wave;     // 0..7
    const int k0   = ks * 256;

    const float* Ap = ns + ((size_t)(mtw * 16 + l16) * Usz + u) * Nsz + k0;
    const float* Bp = Wout + (size_t)u * Nsz * Osz + (size_t)k0 * Osz + ot * 16 + l16;

    f32x4 acc = {};
    for (int s = 0; s < 8; ++s) {
        const int kb = s * 32 + kgl * 8;
        const F8 a = ld8c(Ap + kb);
        const F8 b = ld8s(Bp + (size_t)kb * Osz, Osz);
        acc = __builtin_amdgcn_mfma_f32_16x16x32_bf16(pkF8(a, 1.f), pkF8(b, 1.f), acc, 0, 0, 0);
    }

    float* base = part + ((size_t)ks * 16 + u) * 128 * 256;
    const int gcol = ot * 16 + l16;
    #pragma unroll
    for (int rg = 0; rg < 4; rg++) {
        const int grow = mtw * 16 + kgl * 4 + rg;
        base[(size_t)grow * 256 + gcol] = acc[rg];
    }
}

// sum 4 out-partials -> out1. 512 blocks x 256 thr.
__global__ __launch_bounds__(256)
void out_reduce(const float* __restrict__ part, float* __restrict__ out1)
{
    const size_t i = (size_t)blockIdx.x * 256 + threadIdx.x;   // 0..131071
    const size_t base = i * 4;                 // flat [m][u][o]
    const int m = (int)(base >> 12);
    const int u = (int)((base >> 8) & 15);
    const int o = (int)(base & 255);

    const size_t pb = ((size_t)u * 128 + m) * 256 + o;
    const size_t slab = (size_t)16 * 128 * 256;
    f32x4 s = *(const f32x4*)(part + pb);
    s += *(const f32x4*)(part + pb + slab);
    s += *(const f32x4*)(part + pb + 2 * slab);
    s += *(const f32x4*)(part + pb + 3 * slab);
    *(f32x4*)(out1 + base) = s;
}

// ================= FALLBACK PATH (ws too small): R8 kernels =================
struct Step { F8 a0, a1, b0, b1; };

__global__ __launch_bounds__(256)
void state_mfma(const float* __restrict__ X, const float* __restrict__ state,
                const float* __restrict__ W, const float* __restrict__ Win,
                const float* __restrict__ bias, const float* __restrict__ sr,
                const float* __restrict__ lr, float* __restrict__ out0)
{
    const int id = blockIdx.x;
    const int u  = id & 15;
    const int nt = (id >> 4) & 15;
    const int mt = id >> 8;

    const int tid  = threadIdx.x;
    const int wave = tid >> 6, lane = tid & 63;
    const int l16  = lane & 15, kgl = lane >> 4;
    const int wm = wave & 1, wn = wave >> 1;

    const int row0 = mt * 64 + wm * 32 + l16;
    const int col0 = nt * 64 + wn * 32 + l16;
    const float sru = sr[u];

    const float* Ax0 = X + ((size_t)row0 * Usz + u) * Dsz;
    const float* Ax1 = X + ((size_t)(row0 + 16) * Usz + u) * Dsz;
    const float* Ae0 = state + ((size_t)row0 * Usz + u) * Nsz;
    const float* Ae1 = state + ((size_t)(row0 + 16) * Usz + u) * Nsz;
    const float* Bf  = Win + (size_t)u * Dsz * Nsz + col0;
    const float* Be  = W   + (size_t)u * Nsz * Nsz + col0;

    f32x4 acc[2][2] = {};
    for (int s = 0; s < 40; ++s) {
        const int kb = s * 32 + kgl * 8;
        F8 a0, a1, b0, b1;
        if (kb < Dsz) {
            a0 = ld8c(Ax0 + kb); a1 = ld8c(Ax1 + kb);
            const float* pb = Bf + (size_t)kb * Nsz;
            b0 = ld8s(pb, Nsz); b1 = ld8s(pb + 16, Nsz);
        } else {
            const int kk = kb - Dsz;
            a0 = ld8c(Ae0 + kk); a1 = ld8c(Ae1 + kk);
            const float* pb = Be + (size_t)kk * Nsz;
            b0 = ld8s(pb, Nsz); b1 = ld8s(pb + 16, Nsz);
        }
        const float asc = (s < 8) ? 1.f : sru;
        const bf16x8 af0 = pkF8(a0, asc), af1 = pkF8(a1, asc);
        const bf16x8 bf0 = pkF8(b0, 1.f), bf1 = pkF8(b1, 1.f);
        acc[0][0] = __builtin_amdgcn_mfma_f32_16x16x32_bf16(af0, bf0, acc[0][0], 0, 0, 0);
        acc[0][1] = __builtin_amdgcn_mfma_f32_16x16x32_bf16(af0, bf1, acc[0][1], 0, 0, 0);
        acc[1][0] = __builtin_amdgcn_mfma_f32_16x16x32_bf16(af1, bf0, acc[1][0], 0, 0, 0);
        acc[1][1] = __builtin_amdgcn_mfma_f32_16x16x32_bf16(af1, bf1, acc[1][1], 0, 0, 0);
    }
    #pragma unroll
    for (int ni = 0; ni < 2; ni++) {
        const int gcol = nt * 64 + wn * 32 + ni * 16 + l16;
        const float bi = bias[u * Nsz + gcol];
        #pragma unroll
        for (int mi = 0; mi < 2; mi++) {
            #pragma unroll
            for (int rg = 0; rg < 4; rg++) {
                const int grow = mt * 64 + wm * 32 + mi * 16 + kgl * 4 + rg;
                const size_t idx = ((size_t)grow * Usz + u) * Nsz + gcol;
                const float th = tanhf(acc[mi][ni][rg] + bi);
                out0[idx] = (1.f - lr[grow * Usz + u]) * state[idx] + lr[grow * Usz + u] * th;
            }
        }
    }
}

__global__ __launch_bounds__(256)
void out_mfma(const float* __restrict__ ns, const float* __restrict__ Wout,
              float* __restrict__ out1)
{
    const int w  = blockIdx.x * 4 + (threadIdx.x >> 6);
    const int u  = w & 15;
    const int ot = (w >> 4) & 15;
    const int mtw = w >> 8;

    const int lane = threadIdx.x & 63;
    const int l16  = lane & 15, kgl = lane >> 4;

    const float* Ap = ns + ((size_t)(mtw * 16 + l16) * Usz + u) * Nsz;
    const float* Bp = Wout + (size_t)u * Nsz * Osz + ot * 16 + l16;

    f32x4 acc = {};
    for (int s = 0; s < 32; ++s) {
        const int kb = s * 32 + kgl * 8;
        const F8 a = ld8c(Ap + kb);
        const F8 b = ld8s(Bp + (size_t)kb * Osz, Osz);
        acc = __builtin_amdgcn_mfma_f32_16x16x32_bf16(pkF8(a, 1.f), pkF8(b, 1.f), acc, 0, 0, 0);
    }
    const int gcol = ot * 16 + l16;
    #pragma unroll
    for (int rg = 0; rg < 4; rg++) {
        const int grow = mtw * 16 + kgl * 4 + rg;
        out1[((size_t)grow * Usz + u) * Osz + gcol] = acc[rg];
    }
}

extern "C" void kernel_launch(void* const* d_in, const int* in_sizes, int n_in,
                              void* d_out, int out_size, void* d_ws, size_t ws_size,
                              hipStream_t stream)
{
    (void)in_sizes; (void)n_in; (void)out_size;
    const float* X     = (const float*)d_in[0];
    const float* state = (const float*)d_in[1];
    const float* W     = (const float*)d_in[2];
    const float* Win   = (const float*)d_in[3];
    const float* bias  = (const float*)d_in[4];
    const float* Wout  = (const float*)d_in[5];
    const float* sr    = (const float*)d_in[6];
    const float* alr   = (const float*)d_in[7];
    const float* temp  = (const float*)d_in[8];

    float* out0 = (float*)d_out;                      // (B,U,N)
    float* out1 = out0 + (size_t)Bsz * Usz * Nsz;     // (B,U,O)
    float* lr   = (float*)d_ws;                       // 8 KB

    const size_t p1_off = 8192;
    const size_t p1_bytes = (size_t)4 * 16 * 128 * 1024 * 4;   // 32 MiB
    const size_t p2_off = p1_off + p1_bytes;
    const size_t p2_bytes = (size_t)4 * 16 * 128 * 256 * 4;    // 8 MiB

    lr_kernel<<<Bsz, 256, 0, stream>>>(X, alr, temp, lr);

    if (ws_size >= p2_off + p2_bytes) {
        float* p1 = (float*)((char*)d_ws + p1_off);
        float* p2 = (float*)((char*)d_ws + p2_off);
        state_split<<<2048, 256, 0, stream>>>(X, state, W, Win, sr, p1);
        state_reduce<<<2048, 256, 0, stream>>>(p1, state, bias, lr, out0);
        out_split<<<2048, 256, 0, stream>>>(out0, Wout, p2);
        out_reduce<<<512, 256, 0, stream>>>(p2, out1);
    } else {
        state_mfma<<<512, 256, 0, stream>>>(X, state, W, Win, bias, sr, lr, out0);
        out_mfma<<<512, 256, 0, stream>>>(out0, Wout, out1);
    }
}

// Round 10
// 194.277 us; speedup vs baseline: 1.1687x; 1.1687x over previous
//
#include <hip/hip_runtime.h>
#include <math.h>

#define Bsz 128
#define Usz 16
#define Dsz 256
#define Nsz 1024
#define Osz 256
#define BK  64

typedef __attribute__((ext_vector_type(2))) unsigned int u32x2;
typedef __attribute__((ext_vector_type(4))) unsigned int u32x4;
typedef __attribute__((ext_vector_type(4))) float f32x4;
typedef __attribute__((ext_vector_type(8))) short bf16x8;

union cell_u { u32x4 u; bf16x8 b; };
union cell2_u { u32x2 u; };

__device__ __forceinline__ unsigned int fbits(float f) {
    union { float f; unsigned int u; } v; v.f = f; return v.u;
}
// pack two f32 -> (bf16(hi)<<16)|bf16(lo) by truncation: 1 v_perm_b32
__device__ __forceinline__ unsigned int pk(float lo, float hi) {
    return __builtin_amdgcn_perm(fbits(hi), fbits(lo), 0x07060302u);
}
__device__ __forceinline__ u32x2 pk4(f32x4 v, float s) {
    v *= s;
    u32x2 r; r[0] = pk(v[0], v[1]); r[1] = pk(v[2], v[3]);
    return r;
}
// 8 k-strided scalar loads -> bf16x8 B-fragment (lane: n fixed, k contiguous)
__device__ __forceinline__ bf16x8 ldB8(const float* p, size_t str) {
    const float x0 = p[0],       x1 = p[str],     x2 = p[2*str], x3 = p[3*str];
    const float x4 = p[4*str],   x5 = p[5*str],   x6 = p[6*str], x7 = p[7*str];
    cell_u r;
    r.u[0] = pk(x0, x1); r.u[1] = pk(x2, x3);
    r.u[2] = pk(x4, x5); r.u[3] = pk(x6, x7);
    return r.b;
}

// ---------------- lr = softmax_u(X·alr / T) ----------------
__global__ __launch_bounds__(256)
void lr_kernel(const float* __restrict__ X, const float* __restrict__ alr,
               const float* __restrict__ temp, float* __restrict__ lr)
{
    const int b = blockIdx.x;
    const int t = threadIdx.x;
    const int u = t >> 4;
    const int l = t & 15;
    const float* xp = X + ((size_t)b * Usz + u) * Dsz;
    const float* ap = alr + (size_t)u * Dsz;
    float s = 0.f;
    for (int d = l; d < Dsz; d += 16) s += xp[d] * ap[d];
    s += __shfl_down(s, 8, 16);
    s += __shfl_down(s, 4, 16);
    s += __shfl_down(s, 2, 16);
    s += __shfl_down(s, 1, 16);
    __shared__ float logits[16];
    if (l == 0) logits[u] = s;
    __syncthreads();
    if (t < 16) {
        const float T = temp[0];
        float m = -1e30f;
        #pragma unroll
        for (int i = 0; i < 16; i++) m = fmaxf(m, logits[i] / T);
        float sum = 0.f;
        #pragma unroll
        for (int i = 0; i < 16; i++) sum += expf(logits[i] / T - m);
        lr[(size_t)b * Usz + t] = expf(logits[t] / T - m) / sum;
    }
}

// ---- state GEMM: C = [X | state*sr] · [Win ; W], K=1280, epilogue fused ----
// M-tile = 128 (B/W read once), N-tile 64, BK=64, grid 256 = nt16 x u16.
// A staged via LDS with minimal-line coalesced dwordx4 (4 rows x 256B = 8
// lines per wave-instr), bf16-packed, double-buffered, 1 barrier/step,
// register prefetch distance 1. B loaded direct-to-register k-strided
// (4-line instrs, each element read once chip-wide). Wave = 64m x 32n.
__global__ __launch_bounds__(256)
void state_gemm(const float* __restrict__ X, const float* __restrict__ state,
                const float* __restrict__ W, const float* __restrict__ Win,
                const float* __restrict__ bias, const float* __restrict__ sr,
                const float* __restrict__ lr, float* __restrict__ out0)
{
    const int id = blockIdx.x;
    const int u  = id & 15;
    const int nt = id >> 4;

    const int tid  = threadIdx.x;
    const int wave = tid >> 6, lane = tid & 63;
    const int l16  = lane & 15, kgl = lane >> 4;
    const int wm = wave & 1, wn = wave >> 1;

    // A LDS: [m128][k64 + pad8] bf16, x2 buffers = 36 KB
    __shared__ unsigned short As[2][128 * 72];

    const float sru = sr[u];

    // staging map: thread (r0 = tid>>4, c = tid&15); loads rows r0+16i,
    // 16B k-seg c. One wave-instr = 4 rows x full 256B row-step = 8 lines.
    const int r0 = tid >> 4;
    const int c  = tid & 15;

    f32x4 ra[8];   // next-step A tile slice (constant-indexed -> VGPRs)

    auto ldA = [&](int s) {
        const int k0 = s * BK;
        if (k0 < Dsz) {
            const float* base = X + ((size_t)r0 * Usz + u) * Dsz + k0 + c * 4;
            #pragma unroll
            for (int i = 0; i < 8; i++)
                ra[i] = *(const f32x4*)(base + (size_t)16 * i * Usz * Dsz);
        } else {
            const float* base = state + ((size_t)r0 * Usz + u) * Nsz + (k0 - Dsz) + c * 4;
            #pragma unroll
            for (int i = 0; i < 8; i++)
                ra[i] = *(const f32x4*)(base + (size_t)16 * i * Usz * Nsz);
        }
    };
    auto wrA = [&](int p, float sc) {
        #pragma unroll
        for (int i = 0; i < 8; i++)
            *(u32x2*)&As[p][(r0 + 16 * i) * 72 + c * 4] = pk4(ra[i], sc);
    };

    f32x4 acc[4][2] = {};

    auto comp = [&](int s, int p) {
        const int k0 = s * BK;
        const float* bbase = (k0 < Dsz)
            ? Win + (size_t)u * Dsz * Nsz + (size_t)k0 * Nsz
            : W   + (size_t)u * Nsz * Nsz + (size_t)(k0 - Dsz) * Nsz;
        const int col = nt * 64 + wn * 32 + l16;
        #pragma unroll
        for (int kk = 0; kk < 2; kk++) {
            const float* bp = bbase + (size_t)(kk * 32 + kgl * 8) * Nsz + col;
            const bf16x8 bf0 = ldB8(bp, Nsz);
            const bf16x8 bf1 = ldB8(bp + 16, Nsz);
            #pragma unroll
            for (int mi = 0; mi < 4; mi++) {
                const bf16x8 af = *(const bf16x8*)&As[p][(wm * 64 + mi * 16 + l16) * 72 + kk * 32 + kgl * 8];
                acc[mi][0] = __builtin_amdgcn_mfma_f32_16x16x32_bf16(af, bf0, acc[mi][0], 0, 0, 0);
                acc[mi][1] = __builtin_amdgcn_mfma_f32_16x16x32_bf16(af, bf1, acc[mi][1], 0, 0, 0);
            }
        }
    };

    ldA(0); wrA(0, 1.f);
    ldA(1);
    __syncthreads();
    for (int s = 0; s < 20; s++) {
        const int p = s & 1;
        if (s + 1 < 20) wrA(p ^ 1, (s + 1 < 4) ? 1.f : sru);  // ra holds step s+1
        if (s + 2 < 20) ldA(s + 2);
        comp(s, p);
        __syncthreads();
    }

    // C/D layout: col=lane&15, row=(lane>>4)*4+reg (HW-verified R3-R9)
    #pragma unroll
    for (int ni = 0; ni < 2; ni++) {
        const int gcol = nt * 64 + wn * 32 + ni * 16 + l16;
        const float bi = bias[u * Nsz + gcol];
        #pragma unroll
        for (int mi = 0; mi < 4; mi++) {
            #pragma unroll
            for (int rg = 0; rg < 4; rg++) {
                const int grow = wm * 64 + mi * 16 + kgl * 4 + rg;
                const size_t idx = ((size_t)grow * Usz + u) * Nsz + gcol;
                const float th = tanhf(acc[mi][ni][rg] + bi);
                const float lv = lr[grow * Usz + u];
                out0[idx] = (1.f - lv) * state[idx] + lv * th;
            }
        }
    }
}

// ---- out GEMM: ns(128xK=1024) · Wout(Kx256), same structure, split-K ----
// grid = ks x ot4 x u16; each block: M128 x N64, nsteps K-steps of 64.
__global__ __launch_bounds__(256)
void out_gemm(const float* __restrict__ ns, const float* __restrict__ Wout,
              float* __restrict__ dst, int nsteps, int partial)
{
    const int id = blockIdx.x;
    const int u  = id & 15;
    const int ot = (id >> 4) & 3;
    const int ks = id >> 6;
    const int kbase = ks * nsteps * BK;

    const int tid  = threadIdx.x;
    const int wave = tid >> 6, lane = tid & 63;
    const int l16  = lane & 15, kgl = lane >> 4;
    const int wm = wave & 1, wn = wave >> 1;

    __shared__ unsigned short As[2][128 * 72];

    const int r0 = tid >> 4;
    const int c  = tid & 15;

    f32x4 ra[8];
    auto ldA = [&](int s) {
        const float* base = ns + ((size_t)r0 * Usz + u) * Nsz + kbase + s * BK + c * 4;
        #pragma unroll
        for (int i = 0; i < 8; i++)
            ra[i] = *(const f32x4*)(base + (size_t)16 * i * Usz * Nsz);
    };
    auto wrA = [&](int p) {
        #pragma unroll
        for (int i = 0; i < 8; i++)
            *(u32x2*)&As[p][(r0 + 16 * i) * 72 + c * 4] = pk4(ra[i], 1.f);
    };

    f32x4 acc[4][2] = {};
    auto comp = [&](int s, int p) {
        const float* bbase = Wout + (size_t)u * Nsz * Osz + (size_t)(kbase + s * BK) * Osz;
        const int col = ot * 64 + wn * 32 + l16;
        #pragma unroll
        for (int kk = 0; kk < 2; kk++) {
            const float* bp = bbase + (size_t)(kk * 32 + kgl * 8) * Osz + col;
            const bf16x8 bf0 = ldB8(bp, Osz);
            const bf16x8 bf1 = ldB8(bp + 16, Osz);
            #pragma unroll
            for (int mi = 0; mi < 4; mi++) {
                const bf16x8 af = *(const bf16x8*)&As[p][(wm * 64 + mi * 16 + l16) * 72 + kk * 32 + kgl * 8];
                acc[mi][0] = __builtin_amdgcn_mfma_f32_16x16x32_bf16(af, bf0, acc[mi][0], 0, 0, 0);
                acc[mi][1] = __builtin_amdgcn_mfma_f32_16x16x32_bf16(af, bf1, acc[mi][1], 0, 0, 0);
            }
        }
    };

    ldA(0); wrA(0);
    if (nsteps > 1) ldA(1);
    __syncthreads();
    for (int s = 0; s < nsteps; s++) {
        const int p = s & 1;
        if (s + 1 < nsteps) wrA(p ^ 1);
        if (s + 2 < nsteps) ldA(s + 2);
        comp(s, p);
        __syncthreads();
    }

    #pragma unroll
    for (int ni = 0; ni < 2; ni++) {
        const int gcol = ot * 64 + wn * 32 + ni * 16 + l16;
        #pragma unroll
        for (int mi = 0; mi < 4; mi++) {
            #pragma unroll
            for (int rg = 0; rg < 4; rg++) {
                const int grow = wm * 64 + mi * 16 + kgl * 4 + rg;
                if (partial)
                    dst[(((size_t)ks * 16 + u) * 128 + grow) * 256 + gcol] = acc[mi][ni][rg];
                else
                    dst[((size_t)grow * Usz + u) * Osz + gcol] = acc[mi][ni][rg];
            }
        }
    }
}

// ---- sum 4 out-partials -> out1. 512 blocks x 256 thr ----
__global__ __launch_bounds__(256)
void out_reduce(const float* __restrict__ part, float* __restrict__ out1)
{
    const size_t i = (size_t)blockIdx.x * 256 + threadIdx.x;   // 0..131071
    const size_t base = i * 4;                 // flat [m][u][o]
    const int m = (int)(base >> 12);
    const int u = (int)((base >> 8) & 15);
    const int o = (int)(base & 255);

    const size_t pb = ((size_t)u * 128 + m) * 256 + o;
    const size_t slab = (size_t)16 * 128 * 256;
    f32x4 s = *(const f32x4*)(part + pb);
    s += *(const f32x4*)(part + pb + slab);
    s += *(const f32x4*)(part + pb + 2 * slab);
    s += *(const f32x4*)(part + pb + 3 * slab);
    *(f32x4*)(out1 + base) = s;
}

extern "C" void kernel_launch(void* const* d_in, const int* in_sizes, int n_in,
                              void* d_out, int out_size, void* d_ws, size_t ws_size,
                              hipStream_t stream)
{
    (void)in_sizes; (void)n_in; (void)out_size;
    const float* X     = (const float*)d_in[0];
    const float* state = (const float*)d_in[1];
    const float* W     = (const float*)d_in[2];
    const float* Win   = (const float*)d_in[3];
    const float* bias  = (const float*)d_in[4];
    const float* Wout  = (const float*)d_in[5];
    const float* sr    = (const float*)d_in[6];
    const float* alr   = (const float*)d_in[7];
    const float* temp  = (const float*)d_in[8];

    float* out0 = (float*)d_out;                      // (B,U,N)
    float* out1 = out0 + (size_t)Bsz * Usz * Nsz;     // (B,U,O)
    float* lr   = (float*)d_ws;                       // 8 KB

    const size_t p_off   = 8192;
    const size_t p_bytes = (size_t)4 * 16 * 128 * 256 * 4;   // 8 MiB

    lr_kernel<<<Bsz, 256, 0, stream>>>(X, alr, temp, lr);
    state_gemm<<<256, 256, 0, stream>>>(X, state, W, Win, bias, sr, lr, out0);

    if (ws_size >= p_off + p_bytes) {
        float* part = (float*)((char*)d_ws + p_off);
        out_gemm<<<256, 256, 0, stream>>>(out0, Wout, part, 4, 1);    // ks4 x ot4 x u16
        out_reduce<<<512, 256, 0, stream>>>(part, out1);
    } else {
        out_gemm<<<64, 256, 0, stream>>>(out0, Wout, out1, 16, 0);    // ks1
    }
}